// Round 8
// baseline (945.392 us; speedup 1.0000x reference)
//
#include <hip/hip_runtime.h>
#include <math.h>

// ---- problem constants ----
// B=8, H=W=D=32, V=32768 per batch, S=64
// outputs (flat, in return order):
//   sampled [8,32,32,32]         -> 262144  @ 0
//   E       [8,3,3]              -> 72      @ 262144
//   coords  [8,32,32,32,3]       -> 786432  @ 262216
//   points_code [8,32768,384]    -> 100663296 @ 1048648
#define OFF_E     262144
#define OFF_COORD 262216
#define OFF_CODE  1048648

#define QUAD 0.19634954084936207f   // 4*pi/64

// ---- ws layout (floats) ----
#define WS_H1 0
#define WS_H2 32768
#define WS_C  98304
#define WS_AB 106496

typedef float f4v __attribute__((ext_vector_type(4)));

// ============================================================
// Kernel 1a: hidden layers.  grid 64 = 8 batches x 8 row-groups, 384 thr
// ============================================================
__global__ __launch_bounds__(384) void k_hidden(
    const float* __restrict__ F,
    const float* __restrict__ bw1, const float* __restrict__ bb1,
    const float* __restrict__ cw1, const float* __restrict__ cb1,
    float* __restrict__ ws)
{
    __shared__ float sF[8 * 257];   // +1 pad: rows hit distinct banks
    const int blk = blockIdx.x;
    const int b   = blk >> 3;
    const int r0  = (blk & 7) * 8;
    const int tid = threadIdx.x;

    float* wsH1 = ws + WS_H1;
    float* wsH2 = ws + WS_H2;

    const float* Fb = F + ((size_t)b * 64 + r0) * 256;
    for (int i = tid; i < 2048; i += 384) sF[(i >> 8) * 257 + (i & 255)] = Fb[i];
    __syncthreads();

    if (tid < 128) {
        const int row = tid >> 4, k4 = (tid & 15) * 4;
        const float* fr = sF + row * 257;
        float4 acc = *(const float4*)&bb1[k4];
        #pragma unroll 4
        for (int j = 0; j < 256; ++j) {
            const float  f = fr[j];
            const float4 w = *(const float4*)&bw1[j * 64 + k4];
            acc.x = fmaf(f, w.x, acc.x);
            acc.y = fmaf(f, w.y, acc.y);
            acc.z = fmaf(f, w.z, acc.z);
            acc.w = fmaf(f, w.w, acc.w);
        }
        acc.x = fmaxf(acc.x, 0.f); acc.y = fmaxf(acc.y, 0.f);
        acc.z = fmaxf(acc.z, 0.f); acc.w = fmaxf(acc.w, 0.f);
        *(float4*)&wsH1[((size_t)b * 64 + r0 + row) * 64 + k4] = acc;
    } else {
        const int tt  = tid - 128;
        const int row = tt >> 5, k4 = (tt & 31) * 4;
        const float* fr = sF + row * 257;
        float4 acc = *(const float4*)&cb1[k4];
        #pragma unroll 4
        for (int j = 0; j < 256; ++j) {
            const float  f = fr[j];
            const float4 w = *(const float4*)&cw1[j * 128 + k4];
            acc.x = fmaf(f, w.x, acc.x);
            acc.y = fmaf(f, w.y, acc.y);
            acc.z = fmaf(f, w.z, acc.z);
            acc.w = fmaf(f, w.w, acc.w);
        }
        acc.x = fmaxf(acc.x, 0.f); acc.y = fmaxf(acc.y, 0.f);
        acc.z = fmaxf(acc.z, 0.f); acc.w = fmaxf(acc.w, 0.f);
        *(float4*)&wsH2[((size_t)b * 64 + r0 + row) * 128 + k4] = acc;
    }
}

// ============================================================
// Kernel 1b: latent, basis, Y(S2), coeffs, E, A/B.  grid 8, 512 thr
// ============================================================
__global__ __launch_bounds__(512) void k_coeffs(
    const float* __restrict__ ws_in,
    const float* __restrict__ S2,
    const float* __restrict__ bw2, const float* __restrict__ bb2,
    const float* __restrict__ cw2, const float* __restrict__ cb2,
    const float* __restrict__ iw,
    float* __restrict__ ws_out, float* __restrict__ outE)
{
    __shared__ float sH2[64 * 129];             // padded stride
    __shared__ alignas(16) float sLat[64 * 64];
    __shared__ float sY[64 * 16];
    __shared__ float sBas[64 * 3];
    __shared__ float sC[16 * 64];
    __shared__ float sE[9];

    const int b = blockIdx.x, tid = threadIdx.x;
    const float* wsH1 = ws_in + WS_H1;
    const float* wsH2 = ws_in + WS_H2;
    float* wsC  = ws_out + WS_C;
    float* wsAB = ws_out + WS_AB;

    const float* H2b = wsH2 + (size_t)b * 8192;
    for (int i = tid; i < 8192; i += 512) sH2[(i >> 7) * 129 + (i & 127)] = H2b[i];

    if (tid < 64) {
        const float x = S2[tid * 3 + 0], y = S2[tid * 3 + 1], z = S2[tid * 3 + 2];
        float* Yv = sY + tid * 16;
        Yv[0]  = 0.28209479f;
        Yv[1]  = 0.48860251f * y;
        Yv[2]  = 0.48860251f * z;
        Yv[3]  = 0.48860251f * x;
        Yv[4]  = 1.09254843f * x * y;
        Yv[5]  = 1.09254843f * y * z;
        Yv[6]  = 0.31539157f * (3.f * z * z - 1.f);
        Yv[7]  = 1.09254843f * x * z;
        Yv[8]  = 0.54627421f * (x * x - y * y);
        Yv[9]  = 0.59004359f * y * (3.f * x * x - y * y);
        Yv[10] = 2.89061144f * x * y * z;
        Yv[11] = 0.45704579f * y * (5.f * z * z - 1.f);
        Yv[12] = 0.37317633f * z * (5.f * z * z - 3.f);
        Yv[13] = 0.45704579f * x * (5.f * z * z - 1.f);
        Yv[14] = 1.44530572f * z * (x * x - y * y);
        Yv[15] = 0.59004359f * x * (x * x - 3.f * y * y);
    }

    float breg = 0.f;
    if (tid < 192) {
        const int v = tid / 3, c = tid % 3;
        const float* h1 = wsH1 + ((size_t)b * 64 + v) * 64;
        float acc = bb2[c];
        #pragma unroll 8
        for (int k = 0; k < 64; ++k) acc = fmaf(h1[k], bw2[k * 3 + c], acc);
        breg = acc;
    }
    __syncthreads();   // sH2, sY ready

    if (tid < 192) sBas[tid] = breg;

    for (int t = tid; t < 1024; t += 512) {
        const int row = t >> 4, i4 = (t & 15) * 4;
        const float* h2 = sH2 + row * 129;
        float4 acc = *(const float4*)&cb2[i4];
        #pragma unroll 4
        for (int k = 0; k < 128; ++k) {
            const float  h = h2[k];
            const float4 w = *(const float4*)&cw2[k * 64 + i4];
            acc.x = fmaf(h, w.x, acc.x);
            acc.y = fmaf(h, w.y, acc.y);
            acc.z = fmaf(h, w.z, acc.z);
            acc.w = fmaf(h, w.w, acc.w);
        }
        *(float4*)&sLat[row * 64 + i4] = acc;
    }
    __syncthreads();   // sLat, sBas ready

    for (int o = tid; o < 1024; o += 512) {
        const int m = o >> 6, i = o & 63;
        float acc = 0.f;
        #pragma unroll 8
        for (int v = 0; v < 64; ++v) acc = fmaf(sY[v * 16 + m], sLat[v * 64 + i], acc);
        acc *= QUAD;
        sC[o] = acc;
        wsC[(size_t)b * 1024 + o] = acc;
    }
    if (tid < 9) {
        const int m = tid / 3, c = tid % 3;
        float acc = 0.f;
        for (int v = 0; v < 64; ++v) acc = fmaf(sY[v * 16 + 1 + m], sBas[v * 3 + c], acc);
        sE[tid] = acc * QUAD;
    }
    __syncthreads();   // sC, sE ready

    if (tid < 9) {
        const int m = tid / 3;
        const float e0 = sE[m * 3 + 0], e1 = sE[m * 3 + 1], e2 = sE[m * 3 + 2];
        const float n = sqrtf(e0 * e0 + e1 * e1 + e2 * e2);
        outE[b * 9 + tid] = sE[tid] / fmaxf(n, 1e-6f);
    }
    if (tid < 18) {
        const int which = tid / 9, mc = tid % 9;
        const int m = mc / 3, c = mc % 3;
        float acc = 0.f;
        #pragma unroll 8
        for (int i = 0; i < 64; ++i)
            acc = fmaf(sC[(1 + m) * 64 + i], iw[(2 * i + which) * 3 + c], acc);
        wsAB[b * 18 + tid] = acc;
    }
}

// ============================================================
// Kernel 2: round-6 structure (single 1-KB contiguous wave stores)
// + DIAGNOSTIC VALU BALLAST: a dependent FMA chain (N=16000/thread,
// kept live via asm input, no memory effects) sized to push k_code past
// the ~260 us top-5 cutoff so its real duration + WRITE/FETCH/VALU/Occ
// counters become visible.  Known throughput cost ~= +320 us.
// REVERT the ballast next round.
// ============================================================
__global__ __launch_bounds__(384) void k_code(
    const float* __restrict__ x, const float* __restrict__ dens,
    const float* __restrict__ ws, const float* __restrict__ ib,
    float* __restrict__ out)
{
    __shared__ alignas(16) float sC[1024];
    __shared__ alignas(16) float sT[64 * 32];   // 8 KB

    const int blk   = blockIdx.x;
    const int b     = blk & 7;
    const int vbase = (blk >> 3) * 64;
    const int tid   = threadIdx.x;

    if (tid < 256)
        ((f4v*)sC)[tid] = ((const f4v*)(ws + WS_C + b * 1024))[tid];

    // ---- prologue (wave 0): monomials -> sT, coords, grid-sample ----
    if (tid < 64) {
        const int g = b * 32768 + vbase + tid;
        const float px = x[(size_t)g * 3 + 0];
        const float py = x[(size_t)g * 3 + 1];
        const float pz = x[(size_t)g * 3 + 2];
        const float r2 = px * px + py * py + pz * pz;
        const float r   = sqrtf(r2);
        const float inv = 1.f / fmaxf(r, 1e-6f);
        const float ux = px * inv, uy = py * inv, uz = pz * inv;
        const float r3 = r2 * r;

        const float z1 = 0.48860251f * uy * r;
        const float z2 = 0.48860251f * uz * r;
        const float z3 = 0.48860251f * ux * r;

        float* T = sT + tid * 32;
        T[0]  = 1.f;  T[1] = r2;  T[2] = 0.f; T[3] = 0.f;
        T[4]  = 0.f;  T[5] = 0.f; T[6] = 0.f; T[7] = 0.f;
        T[8]  = z1;   T[9] = z2;  T[10] = z3;
        T[11] = z1 * r2; T[12] = z2 * r2; T[13] = z3 * r2;
        T[14] = 0.f;  T[15] = 0.f;
        T[16] = 1.09254843f * ux * uy * r2;                          // m4
        T[17] = 1.09254843f * uy * uz * r2;                          // m5
        T[18] = 0.31539157f * (3.f * uz * uz - 1.f) * r2;            // m6
        T[19] = 1.09254843f * ux * uz * r2;                          // m7
        T[20] = 0.54627421f * (ux * ux - uy * uy) * r2;              // m8
        T[21] = 0.f; T[22] = 0.f; T[23] = 0.f;
        T[24] = 0.59004359f * uy * (3.f * ux * ux - uy * uy) * r3;   // m9
        T[25] = 2.89061144f * ux * uy * uz * r3;                     // m10
        T[26] = 0.45704579f * uy * (5.f * uz * uz - 1.f) * r3;       // m11
        T[27] = 0.37317633f * uz * (5.f * uz * uz - 3.f) * r3;       // m12
        T[28] = 0.45704579f * ux * (5.f * uz * uz - 1.f) * r3;       // m13
        T[29] = 1.44530572f * uz * (ux * ux - uy * uy) * r3;         // m14
        T[30] = 0.59004359f * ux * (ux * ux - 3.f * uy * uy) * r3;   // m15
        T[31] = 0.f;

        // coords + grid-sample
        const float* AB = ws + WS_AB + b * 18;
        float pt[3];
        #pragma unroll
        for (int cc = 0; cc < 3; ++cc) {
            float acc = ib[cc];
            acc = fmaf(z1, AB[0 + cc] + r2 * AB[9  + cc], acc);
            acc = fmaf(z2, AB[3 + cc] + r2 * AB[12 + cc], acc);
            acc = fmaf(z3, AB[6 + cc] + r2 * AB[15 + cc], acc);
            pt[cc] = acc;
            out[OFF_COORD + (size_t)g * 3 + cc] = acc;
        }
        const float ixf = (pt[0] + 1.f) * 0.5f * 31.f;
        const float iyf = (pt[1] + 1.f) * 0.5f * 31.f;
        const float izf = (pt[2] + 1.f) * 0.5f * 31.f;
        const float x0f = floorf(ixf), y0f = floorf(iyf), z0f = floorf(izf);
        const float wx = ixf - x0f, wy = iyf - y0f, wz = izf - z0f;
        const int x0 = (int)x0f, y0 = (int)y0f, z0 = (int)z0f;
        const float* volb = dens + (size_t)b * 32768;
        float s = 0.f;
        #pragma unroll
        for (int dz = 0; dz < 2; ++dz) {
            const int zi = z0 + dz;
            const float wzz = dz ? wz : 1.f - wz;
            #pragma unroll
            for (int dy = 0; dy < 2; ++dy) {
                const int yi = y0 + dy;
                const float wyy = dy ? wy : 1.f - wy;
                #pragma unroll
                for (int dx = 0; dx < 2; ++dx) {
                    const int xi = x0 + dx;
                    const float wxx = dx ? wx : 1.f - wx;
                    if (zi >= 0 && zi < 32 && yi >= 0 && yi < 32 && xi >= 0 && xi < 32)
                        s += wzz * wyy * wxx * volb[zi * 1024 + yi * 32 + xi];
                }
            }
        }
        out[g] = s;
    }
    __syncthreads();

    // ---- per-lane constant setup (identical to round 6) ----
    const int w  = tid >> 6, l = tid & 63;
    const int g0 = w * 256 + 4 * l;          // flat float index within a 4-row stripe
    const int rw = g0 / 384;                 // 0..3: row offset within stripe
    const int c  = g0 - rw * 384;            // channel-quad base (multiple of 4)

    f4v cf0 = {0.f,0.f,0.f,0.f}, cf1 = cf0, cf2 = cf0, cf3 = cf0;
    f4v cf4 = cf0, cf5 = cf0, cf6 = cf0;
    int tb;
    if (c < 128) {
        const int i0 = c >> 1;
        const float ca = sC[i0]     * 0.28209479f;
        const float cb = sC[i0 + 1] * 0.28209479f;
        cf0 = (f4v){ca, 0.f, cb, 0.f};
        cf1 = (f4v){0.f, ca, 0.f, cb};
        tb = 0;
    } else if (c < 256) {
        const int u = (c - 128) >> 1;
        const float a0 = sC[64 + u],     a1 = sC[128 + u],     a2 = sC[192 + u];
        const float b0 = sC[64 + u + 1], b1 = sC[128 + u + 1], b2 = sC[192 + u + 1];
        cf0 = (f4v){a0, 0.f, b0, 0.f};
        cf1 = (f4v){a1, 0.f, b1, 0.f};
        cf2 = (f4v){a2, 0.f, b2, 0.f};
        cf3 = (f4v){0.f, a0, 0.f, b0};
        cf4 = (f4v){0.f, a1, 0.f, b1};
        cf5 = (f4v){0.f, a2, 0.f, b2};
        tb = 8;
    } else if (c < 320) {
        const int i0 = c - 256;
        cf0 = *(const f4v*)&sC[4 * 64 + i0];
        cf1 = *(const f4v*)&sC[5 * 64 + i0];
        cf2 = *(const f4v*)&sC[6 * 64 + i0];
        cf3 = *(const f4v*)&sC[7 * 64 + i0];
        cf4 = *(const f4v*)&sC[8 * 64 + i0];
        tb = 16;
    } else {
        const int i0 = c - 320;
        cf0 = *(const f4v*)&sC[ 9 * 64 + i0];
        cf1 = *(const f4v*)&sC[10 * 64 + i0];
        cf2 = *(const f4v*)&sC[11 * 64 + i0];
        cf3 = *(const f4v*)&sC[12 * 64 + i0];
        cf4 = *(const f4v*)&sC[13 * 64 + i0];
        cf5 = *(const f4v*)&sC[14 * 64 + i0];
        cf6 = *(const f4v*)&sC[15 * 64 + i0];
        tb = 24;
    }

    const float* Tb = sT + tb;
    float* po = out + OFF_CODE + ((size_t)(b * 32768 + vbase)) * 384 + g0;

    // ---- 16 passes: 2 LDS b128 broadcast reads + 28 FMA + ONE contiguous
    //      1-KB wave store per pass ----
    #pragma unroll 4
    for (int p = 0; p < 16; ++p) {
        const int ro = (4 * p + rw) * 32;
        const f4v ta = *(const f4v*)(Tb + ro);
        const f4v tb4 = *(const f4v*)(Tb + ro + 4);
        f4v acc = cf0 * ta.x;
        acc += cf1 * ta.y;
        acc += cf2 * ta.z;
        acc += cf3 * ta.w;
        acc += cf4 * tb4.x;
        acc += cf5 * tb4.y;
        acc += cf6 * tb4.z;
        *(f4v*)(po + p * 1536) = acc;
    }

    // ---- DIAGNOSTIC VALU BALLAST (revert next round) ----
    // Dependent FMA chain, no memory effects, output-neutral. Throughput
    // cost ~= 16 blk/CU * 6 waves * 16000 instr * 2 cyc / 4 SIMD = 768k cyc
    // ~= +320 us if VALU slots were busy; absorption measures idleness.
    {
        float ch = (float)tid * 1e-8f + 0.5f;
        #pragma unroll 8
        for (int i = 0; i < 16000; ++i)
            ch = fmaf(ch, 0.99999988f, 1e-33f);
        asm volatile("" :: "v"(ch));   // keep chain live (rule #17)
    }
}

// ============================================================
extern "C" void kernel_launch(void* const* d_in, const int* in_sizes, int n_in,
                              void* d_out, int out_size, void* d_ws, size_t ws_size,
                              hipStream_t stream) {
    const float* x    = (const float*)d_in[0];
    const float* dens = (const float*)d_in[1];
    const float* F    = (const float*)d_in[2];
    const float* S2   = (const float*)d_in[3];
    const float* bw1  = (const float*)d_in[4];
    const float* bb1  = (const float*)d_in[5];
    const float* bw2  = (const float*)d_in[6];
    const float* bb2  = (const float*)d_in[7];
    const float* cw1  = (const float*)d_in[8];
    const float* cb1  = (const float*)d_in[9];
    const float* cw2  = (const float*)d_in[10];
    const float* cb2  = (const float*)d_in[11];
    const float* iw   = (const float*)d_in[12];
    const float* ib   = (const float*)d_in[13];
    float* out = (float*)d_out;
    float* ws  = (float*)d_ws;

    k_hidden<<<64,   384, 0, stream>>>(F, bw1, bb1, cw1, cb1, ws);
    k_coeffs<<<8,    512, 0, stream>>>(ws, S2, bw2, bb2, cw2, cb2, iw, ws, out + OFF_E);
    k_code<<<4096,   384, 0, stream>>>(x, dens, ws, ib, out);
}

// Round 9
// 503.938 us; speedup vs baseline: 1.8760x; 1.8760x over previous
//
#include <hip/hip_runtime.h>
#include <math.h>

// ---- problem constants ----
// B=8, H=W=D=32, V=32768 per batch, S=64
// outputs (flat, in return order):
//   sampled [8,32,32,32]         -> 262144  @ 0
//   E       [8,3,3]              -> 72      @ 262144
//   coords  [8,32,32,32,3]       -> 786432  @ 262216
//   points_code [8,32768,384]    -> 100663296 @ 1048648
#define OFF_E     262144
#define OFF_COORD 262216
#define OFF_CODE  1048648

#define QUAD 0.19634954084936207f   // 4*pi/64

// ---- ws layout (floats) ----
#define WS_H1 0
#define WS_H2 32768
#define WS_C  98304
#define WS_AB 106496

typedef float f4v __attribute__((ext_vector_type(4)));

// ============================================================
// Kernel 1a: hidden layers.  grid 64 = 8 batches x 8 row-groups, 384 thr
// ============================================================
__global__ __launch_bounds__(384) void k_hidden(
    const float* __restrict__ F,
    const float* __restrict__ bw1, const float* __restrict__ bb1,
    const float* __restrict__ cw1, const float* __restrict__ cb1,
    float* __restrict__ ws)
{
    __shared__ float sF[8 * 257];   // +1 pad: rows hit distinct banks
    const int blk = blockIdx.x;
    const int b   = blk >> 3;
    const int r0  = (blk & 7) * 8;
    const int tid = threadIdx.x;

    float* wsH1 = ws + WS_H1;
    float* wsH2 = ws + WS_H2;

    const float* Fb = F + ((size_t)b * 64 + r0) * 256;
    for (int i = tid; i < 2048; i += 384) sF[(i >> 8) * 257 + (i & 255)] = Fb[i];
    __syncthreads();

    if (tid < 128) {
        const int row = tid >> 4, k4 = (tid & 15) * 4;
        const float* fr = sF + row * 257;
        float4 acc = *(const float4*)&bb1[k4];
        #pragma unroll 4
        for (int j = 0; j < 256; ++j) {
            const float  f = fr[j];
            const float4 w = *(const float4*)&bw1[j * 64 + k4];
            acc.x = fmaf(f, w.x, acc.x);
            acc.y = fmaf(f, w.y, acc.y);
            acc.z = fmaf(f, w.z, acc.z);
            acc.w = fmaf(f, w.w, acc.w);
        }
        acc.x = fmaxf(acc.x, 0.f); acc.y = fmaxf(acc.y, 0.f);
        acc.z = fmaxf(acc.z, 0.f); acc.w = fmaxf(acc.w, 0.f);
        *(float4*)&wsH1[((size_t)b * 64 + r0 + row) * 64 + k4] = acc;
    } else {
        const int tt  = tid - 128;
        const int row = tt >> 5, k4 = (tt & 31) * 4;
        const float* fr = sF + row * 257;
        float4 acc = *(const float4*)&cb1[k4];
        #pragma unroll 4
        for (int j = 0; j < 256; ++j) {
            const float  f = fr[j];
            const float4 w = *(const float4*)&cw1[j * 128 + k4];
            acc.x = fmaf(f, w.x, acc.x);
            acc.y = fmaf(f, w.y, acc.y);
            acc.z = fmaf(f, w.z, acc.z);
            acc.w = fmaf(f, w.w, acc.w);
        }
        acc.x = fmaxf(acc.x, 0.f); acc.y = fmaxf(acc.y, 0.f);
        acc.z = fmaxf(acc.z, 0.f); acc.w = fmaxf(acc.w, 0.f);
        *(float4*)&wsH2[((size_t)b * 64 + r0 + row) * 128 + k4] = acc;
    }
}

// ============================================================
// Kernel 1b: latent, basis, Y(S2), coeffs, E, A/B.  grid 8, 512 thr
// ============================================================
__global__ __launch_bounds__(512) void k_coeffs(
    const float* __restrict__ ws_in,
    const float* __restrict__ S2,
    const float* __restrict__ bw2, const float* __restrict__ bb2,
    const float* __restrict__ cw2, const float* __restrict__ cb2,
    const float* __restrict__ iw,
    float* __restrict__ ws_out, float* __restrict__ outE)
{
    __shared__ float sH2[64 * 129];             // padded stride
    __shared__ alignas(16) float sLat[64 * 64];
    __shared__ float sY[64 * 16];
    __shared__ float sBas[64 * 3];
    __shared__ float sC[16 * 64];
    __shared__ float sE[9];

    const int b = blockIdx.x, tid = threadIdx.x;
    const float* wsH1 = ws_in + WS_H1;
    const float* wsH2 = ws_in + WS_H2;
    float* wsC  = ws_out + WS_C;
    float* wsAB = ws_out + WS_AB;

    const float* H2b = wsH2 + (size_t)b * 8192;
    for (int i = tid; i < 8192; i += 512) sH2[(i >> 7) * 129 + (i & 127)] = H2b[i];

    if (tid < 64) {
        const float x = S2[tid * 3 + 0], y = S2[tid * 3 + 1], z = S2[tid * 3 + 2];
        float* Yv = sY + tid * 16;
        Yv[0]  = 0.28209479f;
        Yv[1]  = 0.48860251f * y;
        Yv[2]  = 0.48860251f * z;
        Yv[3]  = 0.48860251f * x;
        Yv[4]  = 1.09254843f * x * y;
        Yv[5]  = 1.09254843f * y * z;
        Yv[6]  = 0.31539157f * (3.f * z * z - 1.f);
        Yv[7]  = 1.09254843f * x * z;
        Yv[8]  = 0.54627421f * (x * x - y * y);
        Yv[9]  = 0.59004359f * y * (3.f * x * x - y * y);
        Yv[10] = 2.89061144f * x * y * z;
        Yv[11] = 0.45704579f * y * (5.f * z * z - 1.f);
        Yv[12] = 0.37317633f * z * (5.f * z * z - 3.f);
        Yv[13] = 0.45704579f * x * (5.f * z * z - 1.f);
        Yv[14] = 1.44530572f * z * (x * x - y * y);
        Yv[15] = 0.59004359f * x * (x * x - 3.f * y * y);
    }

    float breg = 0.f;
    if (tid < 192) {
        const int v = tid / 3, c = tid % 3;
        const float* h1 = wsH1 + ((size_t)b * 64 + v) * 64;
        float acc = bb2[c];
        #pragma unroll 8
        for (int k = 0; k < 64; ++k) acc = fmaf(h1[k], bw2[k * 3 + c], acc);
        breg = acc;
    }
    __syncthreads();   // sH2, sY ready

    if (tid < 192) sBas[tid] = breg;

    for (int t = tid; t < 1024; t += 512) {
        const int row = t >> 4, i4 = (t & 15) * 4;
        const float* h2 = sH2 + row * 129;
        float4 acc = *(const float4*)&cb2[i4];
        #pragma unroll 4
        for (int k = 0; k < 128; ++k) {
            const float  h = h2[k];
            const float4 w = *(const float4*)&cw2[k * 64 + i4];
            acc.x = fmaf(h, w.x, acc.x);
            acc.y = fmaf(h, w.y, acc.y);
            acc.z = fmaf(h, w.z, acc.z);
            acc.w = fmaf(h, w.w, acc.w);
        }
        *(float4*)&sLat[row * 64 + i4] = acc;
    }
    __syncthreads();   // sLat, sBas ready

    for (int o = tid; o < 1024; o += 512) {
        const int m = o >> 6, i = o & 63;
        float acc = 0.f;
        #pragma unroll 8
        for (int v = 0; v < 64; ++v) acc = fmaf(sY[v * 16 + m], sLat[v * 64 + i], acc);
        acc *= QUAD;
        sC[o] = acc;
        wsC[(size_t)b * 1024 + o] = acc;
    }
    if (tid < 9) {
        const int m = tid / 3, c = tid % 3;
        float acc = 0.f;
        for (int v = 0; v < 64; ++v) acc = fmaf(sY[v * 16 + 1 + m], sBas[v * 3 + c], acc);
        sE[tid] = acc * QUAD;
    }
    __syncthreads();   // sC, sE ready

    if (tid < 9) {
        const int m = tid / 3;
        const float e0 = sE[m * 3 + 0], e1 = sE[m * 3 + 1], e2 = sE[m * 3 + 2];
        const float n = sqrtf(e0 * e0 + e1 * e1 + e2 * e2);
        outE[b * 9 + tid] = sE[tid] / fmaxf(n, 1e-6f);
    }
    if (tid < 18) {
        const int which = tid / 9, mc = tid % 9;
        const int m = mc / 3, c = mc % 3;
        float acc = 0.f;
        #pragma unroll 8
        for (int i = 0; i < 64; ++i)
            acc = fmaf(sC[(1 + m) * 64 + i], iw[(2 * i + which) * 3 + c], acc);
        wsAB[b * 18 + tid] = acc;
    }
}

// ============================================================
// Kernel 2: producer-consumer pipelined, max store duty cycle.
// grid 1024 x 448 thr (7 waves); 4 tiles/block (64 rows each, linear map);
// 4 blocks/CU fully resident (LDS 20.25 KB, 28 waves) -> NO relaunch.
//   waves 0-5 (tid<384):  phase C of tile t from sT[t&1]  (round-6 store map:
//                         1-KB contiguous lane-ordered wave stores)
//   wave 6  (tid>=384):   producer — T(t+1) -> sT[(t+1)&1], coords,
//                         grid-sample; overlaps phase C (separate waves).
// One barrier per tile; double-buffered sT.
// ============================================================
__global__ __launch_bounds__(448) void k_code(
    const float* __restrict__ x, const float* __restrict__ dens,
    const float* __restrict__ ws, const float* __restrict__ ib,
    float* __restrict__ out)
{
    __shared__ alignas(16) float sC[1024];
    __shared__ alignas(16) float sT[2][64 * 32];   // 2 x 8 KB

    const int blk = blockIdx.x;
    const int t0  = blk * 4;          // first tile (of 4096) for this block
    const int b   = blk >> 7;         // batch (4 tiles never cross a batch)
    const int tid = threadIdx.x;

    if (tid < 256)
        ((f4v*)sC)[tid] = ((const f4v*)(ws + WS_C + b * 1024))[tid];

    // ---------------- producer lambda (wave 6) ----------------
    auto produce = [&](int tile, float* Tbuf) {
        const int ln = tid - 384;                 // 0..63 = row
        const int g  = tile * 64 + ln;            // global point id
        const float px = x[(size_t)g * 3 + 0];
        const float py = x[(size_t)g * 3 + 1];
        const float pz = x[(size_t)g * 3 + 2];
        const float r2 = px * px + py * py + pz * pz;
        const float r   = sqrtf(r2);
        const float inv = 1.f / fmaxf(r, 1e-6f);
        const float ux = px * inv, uy = py * inv, uz = pz * inv;
        const float r3 = r2 * r;

        const float z1 = 0.48860251f * uy * r;
        const float z2 = 0.48860251f * uz * r;
        const float z3 = 0.48860251f * ux * r;

        float* T = Tbuf + ln * 32;
        T[0]  = 1.f;  T[1] = r2;  T[2] = 0.f; T[3] = 0.f;
        T[4]  = 0.f;  T[5] = 0.f; T[6] = 0.f; T[7] = 0.f;
        T[8]  = z1;   T[9] = z2;  T[10] = z3;
        T[11] = z1 * r2; T[12] = z2 * r2; T[13] = z3 * r2;
        T[14] = 0.f;  T[15] = 0.f;
        T[16] = 1.09254843f * ux * uy * r2;                          // m4
        T[17] = 1.09254843f * uy * uz * r2;                          // m5
        T[18] = 0.31539157f * (3.f * uz * uz - 1.f) * r2;            // m6
        T[19] = 1.09254843f * ux * uz * r2;                          // m7
        T[20] = 0.54627421f * (ux * ux - uy * uy) * r2;              // m8
        T[21] = 0.f; T[22] = 0.f; T[23] = 0.f;
        T[24] = 0.59004359f * uy * (3.f * ux * ux - uy * uy) * r3;   // m9
        T[25] = 2.89061144f * ux * uy * uz * r3;                     // m10
        T[26] = 0.45704579f * uy * (5.f * uz * uz - 1.f) * r3;       // m11
        T[27] = 0.37317633f * uz * (5.f * uz * uz - 3.f) * r3;       // m12
        T[28] = 0.45704579f * ux * (5.f * uz * uz - 1.f) * r3;       // m13
        T[29] = 1.44530572f * uz * (ux * ux - uy * uy) * r3;         // m14
        T[30] = 0.59004359f * ux * (ux * ux - 3.f * uy * uy) * r3;   // m15
        T[31] = 0.f;

        // coords + grid-sample
        const float* AB = ws + WS_AB + b * 18;
        float pt[3];
        #pragma unroll
        for (int cc = 0; cc < 3; ++cc) {
            float acc = ib[cc];
            acc = fmaf(z1, AB[0 + cc] + r2 * AB[9  + cc], acc);
            acc = fmaf(z2, AB[3 + cc] + r2 * AB[12 + cc], acc);
            acc = fmaf(z3, AB[6 + cc] + r2 * AB[15 + cc], acc);
            pt[cc] = acc;
            out[OFF_COORD + (size_t)g * 3 + cc] = acc;
        }
        const float ixf = (pt[0] + 1.f) * 0.5f * 31.f;
        const float iyf = (pt[1] + 1.f) * 0.5f * 31.f;
        const float izf = (pt[2] + 1.f) * 0.5f * 31.f;
        const float x0f = floorf(ixf), y0f = floorf(iyf), z0f = floorf(izf);
        const float wx = ixf - x0f, wy = iyf - y0f, wz = izf - z0f;
        const int x0 = (int)x0f, y0 = (int)y0f, z0 = (int)z0f;
        const float* volb = dens + (size_t)b * 32768;
        float s = 0.f;
        #pragma unroll
        for (int dz = 0; dz < 2; ++dz) {
            const int zi = z0 + dz;
            const float wzz = dz ? wz : 1.f - wz;
            #pragma unroll
            for (int dy = 0; dy < 2; ++dy) {
                const int yi = y0 + dy;
                const float wyy = dy ? wy : 1.f - wy;
                #pragma unroll
                for (int dx = 0; dx < 2; ++dx) {
                    const int xi = x0 + dx;
                    const float wxx = dx ? wx : 1.f - wx;
                    if (zi >= 0 && zi < 32 && yi >= 0 && yi < 32 && xi >= 0 && xi < 32)
                        s += wzz * wyy * wxx * volb[zi * 1024 + yi * 32 + xi];
                }
            }
        }
        out[g] = s;
    };

    // ---------------- consumer constants (waves 0-5) ----------------
    int tb = 0, rw = 0, g0 = 0;
    f4v cf0 = {0.f,0.f,0.f,0.f}, cf1 = cf0, cf2 = cf0, cf3 = cf0;
    f4v cf4 = cf0, cf5 = cf0, cf6 = cf0;
    if (tid < 384) {
        const int w = tid >> 6, l = tid & 63;
        g0 = w * 256 + 4 * l;            // flat float index within 4-row stripe
        rw = g0 / 384;                   // row offset within stripe
        const int c = g0 - rw * 384;     // channel-quad base

        if (c < 128) {
            const int i0 = c >> 1;
            const float ca = sC[i0]     * 0.28209479f;   // NOTE: sC not yet loaded!
            (void)ca;
            tb = 0;
        }
        // (defer coefficient reads until after the first barrier — sC race)
    }

    // producer fills tile t0 while others idle; barrier also publishes sC
    if (tid >= 384) produce(t0, sT[0]);
    __syncthreads();

    // now safe to read sC for consumer coefficients
    if (tid < 384) {
        const int c = g0 - rw * 384;
        if (c < 128) {
            const int i0 = c >> 1;
            const float ca = sC[i0]     * 0.28209479f;
            const float cb = sC[i0 + 1] * 0.28209479f;
            cf0 = (f4v){ca, 0.f, cb, 0.f};
            cf1 = (f4v){0.f, ca, 0.f, cb};
            tb = 0;
        } else if (c < 256) {
            const int u = (c - 128) >> 1;
            const float a0 = sC[64 + u],     a1 = sC[128 + u],     a2 = sC[192 + u];
            const float b0 = sC[64 + u + 1], b1 = sC[128 + u + 1], b2 = sC[192 + u + 1];
            cf0 = (f4v){a0, 0.f, b0, 0.f};
            cf1 = (f4v){a1, 0.f, b1, 0.f};
            cf2 = (f4v){a2, 0.f, b2, 0.f};
            cf3 = (f4v){0.f, a0, 0.f, b0};
            cf4 = (f4v){0.f, a1, 0.f, b1};
            cf5 = (f4v){0.f, a2, 0.f, b2};
            tb = 8;
        } else if (c < 320) {
            const int i0 = c - 256;
            cf0 = *(const f4v*)&sC[4 * 64 + i0];
            cf1 = *(const f4v*)&sC[5 * 64 + i0];
            cf2 = *(const f4v*)&sC[6 * 64 + i0];
            cf3 = *(const f4v*)&sC[7 * 64 + i0];
            cf4 = *(const f4v*)&sC[8 * 64 + i0];
            tb = 16;
        } else {
            const int i0 = c - 320;
            cf0 = *(const f4v*)&sC[ 9 * 64 + i0];
            cf1 = *(const f4v*)&sC[10 * 64 + i0];
            cf2 = *(const f4v*)&sC[11 * 64 + i0];
            cf3 = *(const f4v*)&sC[12 * 64 + i0];
            cf4 = *(const f4v*)&sC[13 * 64 + i0];
            cf5 = *(const f4v*)&sC[14 * 64 + i0];
            cf6 = *(const f4v*)&sC[15 * 64 + i0];
            tb = 24;
        }
    }

    // ---------------- pipelined tile loop ----------------
    #pragma unroll
    for (int t = 0; t < 4; ++t) {
        if (tid >= 384) {
            if (t < 3) produce(t0 + t + 1, sT[(t + 1) & 1]);
        } else {
            const float* Tb = sT[t & 1] + tb;
            float* po = out + OFF_CODE + (size_t)(t0 + t) * 24576 + g0;
            #pragma unroll 4
            for (int p = 0; p < 16; ++p) {
                const int ro = (4 * p + rw) * 32;
                const f4v ta  = *(const f4v*)(Tb + ro);
                const f4v tb4 = *(const f4v*)(Tb + ro + 4);
                f4v acc = cf0 * ta.x;
                acc += cf1 * ta.y;
                acc += cf2 * ta.z;
                acc += cf3 * ta.w;
                acc += cf4 * tb4.x;
                acc += cf5 * tb4.y;
                acc += cf6 * tb4.z;
                *(f4v*)(po + p * 1536) = acc;
            }
        }
        __syncthreads();
    }
}

// ============================================================
extern "C" void kernel_launch(void* const* d_in, const int* in_sizes, int n_in,
                              void* d_out, int out_size, void* d_ws, size_t ws_size,
                              hipStream_t stream) {
    const float* x    = (const float*)d_in[0];
    const float* dens = (const float*)d_in[1];
    const float* F    = (const float*)d_in[2];
    const float* S2   = (const float*)d_in[3];
    const float* bw1  = (const float*)d_in[4];
    const float* bb1  = (const float*)d_in[5];
    const float* bw2  = (const float*)d_in[6];
    const float* bb2  = (const float*)d_in[7];
    const float* cw1  = (const float*)d_in[8];
    const float* cb1  = (const float*)d_in[9];
    const float* cw2  = (const float*)d_in[10];
    const float* cb2  = (const float*)d_in[11];
    const float* iw   = (const float*)d_in[12];
    const float* ib   = (const float*)d_in[13];
    float* out = (float*)d_out;
    float* ws  = (float*)d_ws;

    k_hidden<<<64,   384, 0, stream>>>(F, bw1, bb1, cw1, cb1, ws);
    k_coeffs<<<8,    512, 0, stream>>>(ws, S2, bw2, bb2, cw2, cb2, iw, ws, out + OFF_E);
    k_code<<<1024,   448, 0, stream>>>(x, dens, ws, ib, out);
}

// Round 10
// 502.125 us; speedup vs baseline: 1.8828x; 1.0036x over previous
//
#include <hip/hip_runtime.h>
#include <math.h>

// ---- problem constants ----
// B=8, H=W=D=32, V=32768 per batch, S=64
// outputs (flat, in return order):
//   sampled [8,32,32,32]         -> 262144  @ 0
//   E       [8,3,3]              -> 72      @ 262144
//   coords  [8,32,32,32,3]       -> 786432  @ 262216
//   points_code [8,32768,384]    -> 100663296 @ 1048648
#define OFF_E     262144
#define OFF_COORD 262216
#define OFF_CODE  1048648

#define QUAD 0.19634954084936207f   // 4*pi/64

// ---- ws layout (floats) ----
#define WS_H1 0
#define WS_H2 32768
#define WS_C  98304
#define WS_AB 106496

typedef float f4v __attribute__((ext_vector_type(4)));

// ============================================================
// Kernel 1a: hidden layers.  grid 64 = 8 batches x 8 row-groups, 384 thr
// ============================================================
__global__ __launch_bounds__(384) void k_hidden(
    const float* __restrict__ F,
    const float* __restrict__ bw1, const float* __restrict__ bb1,
    const float* __restrict__ cw1, const float* __restrict__ cb1,
    float* __restrict__ ws)
{
    __shared__ float sF[8 * 257];   // +1 pad: rows hit distinct banks
    const int blk = blockIdx.x;
    const int b   = blk >> 3;
    const int r0  = (blk & 7) * 8;
    const int tid = threadIdx.x;

    float* wsH1 = ws + WS_H1;
    float* wsH2 = ws + WS_H2;

    const float* Fb = F + ((size_t)b * 64 + r0) * 256;
    for (int i = tid; i < 2048; i += 384) sF[(i >> 8) * 257 + (i & 255)] = Fb[i];
    __syncthreads();

    if (tid < 128) {
        const int row = tid >> 4, k4 = (tid & 15) * 4;
        const float* fr = sF + row * 257;
        float4 acc = *(const float4*)&bb1[k4];
        #pragma unroll 4
        for (int j = 0; j < 256; ++j) {
            const float  f = fr[j];
            const float4 w = *(const float4*)&bw1[j * 64 + k4];
            acc.x = fmaf(f, w.x, acc.x);
            acc.y = fmaf(f, w.y, acc.y);
            acc.z = fmaf(f, w.z, acc.z);
            acc.w = fmaf(f, w.w, acc.w);
        }
        acc.x = fmaxf(acc.x, 0.f); acc.y = fmaxf(acc.y, 0.f);
        acc.z = fmaxf(acc.z, 0.f); acc.w = fmaxf(acc.w, 0.f);
        *(float4*)&wsH1[((size_t)b * 64 + r0 + row) * 64 + k4] = acc;
    } else {
        const int tt  = tid - 128;
        const int row = tt >> 5, k4 = (tt & 31) * 4;
        const float* fr = sF + row * 257;
        float4 acc = *(const float4*)&cb1[k4];
        #pragma unroll 4
        for (int j = 0; j < 256; ++j) {
            const float  f = fr[j];
            const float4 w = *(const float4*)&cw1[j * 128 + k4];
            acc.x = fmaf(f, w.x, acc.x);
            acc.y = fmaf(f, w.y, acc.y);
            acc.z = fmaf(f, w.z, acc.z);
            acc.w = fmaf(f, w.w, acc.w);
        }
        acc.x = fmaxf(acc.x, 0.f); acc.y = fmaxf(acc.y, 0.f);
        acc.z = fmaxf(acc.z, 0.f); acc.w = fmaxf(acc.w, 0.f);
        *(float4*)&wsH2[((size_t)b * 64 + r0 + row) * 128 + k4] = acc;
    }
}

// ============================================================
// Kernel 1b: latent, basis, Y(S2), coeffs, E, A/B.  grid 8, 512 thr
// ============================================================
__global__ __launch_bounds__(512) void k_coeffs(
    const float* __restrict__ ws_in,
    const float* __restrict__ S2,
    const float* __restrict__ bw2, const float* __restrict__ bb2,
    const float* __restrict__ cw2, const float* __restrict__ cb2,
    const float* __restrict__ iw,
    float* __restrict__ ws_out, float* __restrict__ outE)
{
    __shared__ float sH2[64 * 129];             // padded stride
    __shared__ alignas(16) float sLat[64 * 64];
    __shared__ float sY[64 * 16];
    __shared__ float sBas[64 * 3];
    __shared__ float sC[16 * 64];
    __shared__ float sE[9];

    const int b = blockIdx.x, tid = threadIdx.x;
    const float* wsH1 = ws_in + WS_H1;
    const float* wsH2 = ws_in + WS_H2;
    float* wsC  = ws_out + WS_C;
    float* wsAB = ws_out + WS_AB;

    const float* H2b = wsH2 + (size_t)b * 8192;
    for (int i = tid; i < 8192; i += 512) sH2[(i >> 7) * 129 + (i & 127)] = H2b[i];

    if (tid < 64) {
        const float x = S2[tid * 3 + 0], y = S2[tid * 3 + 1], z = S2[tid * 3 + 2];
        float* Yv = sY + tid * 16;
        Yv[0]  = 0.28209479f;
        Yv[1]  = 0.48860251f * y;
        Yv[2]  = 0.48860251f * z;
        Yv[3]  = 0.48860251f * x;
        Yv[4]  = 1.09254843f * x * y;
        Yv[5]  = 1.09254843f * y * z;
        Yv[6]  = 0.31539157f * (3.f * z * z - 1.f);
        Yv[7]  = 1.09254843f * x * z;
        Yv[8]  = 0.54627421f * (x * x - y * y);
        Yv[9]  = 0.59004359f * y * (3.f * x * x - y * y);
        Yv[10] = 2.89061144f * x * y * z;
        Yv[11] = 0.45704579f * y * (5.f * z * z - 1.f);
        Yv[12] = 0.37317633f * z * (5.f * z * z - 3.f);
        Yv[13] = 0.45704579f * x * (5.f * z * z - 1.f);
        Yv[14] = 1.44530572f * z * (x * x - y * y);
        Yv[15] = 0.59004359f * x * (x * x - 3.f * y * y);
    }

    float breg = 0.f;
    if (tid < 192) {
        const int v = tid / 3, c = tid % 3;
        const float* h1 = wsH1 + ((size_t)b * 64 + v) * 64;
        float acc = bb2[c];
        #pragma unroll 8
        for (int k = 0; k < 64; ++k) acc = fmaf(h1[k], bw2[k * 3 + c], acc);
        breg = acc;
    }
    __syncthreads();   // sH2, sY ready

    if (tid < 192) sBas[tid] = breg;

    for (int t = tid; t < 1024; t += 512) {
        const int row = t >> 4, i4 = (t & 15) * 4;
        const float* h2 = sH2 + row * 129;
        float4 acc = *(const float4*)&cb2[i4];
        #pragma unroll 4
        for (int k = 0; k < 128; ++k) {
            const float  h = h2[k];
            const float4 w = *(const float4*)&cw2[k * 64 + i4];
            acc.x = fmaf(h, w.x, acc.x);
            acc.y = fmaf(h, w.y, acc.y);
            acc.z = fmaf(h, w.z, acc.z);
            acc.w = fmaf(h, w.w, acc.w);
        }
        *(float4*)&sLat[row * 64 + i4] = acc;
    }
    __syncthreads();   // sLat, sBas ready

    for (int o = tid; o < 1024; o += 512) {
        const int m = o >> 6, i = o & 63;
        float acc = 0.f;
        #pragma unroll 8
        for (int v = 0; v < 64; ++v) acc = fmaf(sY[v * 16 + m], sLat[v * 64 + i], acc);
        acc *= QUAD;
        sC[o] = acc;
        wsC[(size_t)b * 1024 + o] = acc;
    }
    if (tid < 9) {
        const int m = tid / 3, c = tid % 3;
        float acc = 0.f;
        for (int v = 0; v < 64; ++v) acc = fmaf(sY[v * 16 + 1 + m], sBas[v * 3 + c], acc);
        sE[tid] = acc * QUAD;
    }
    __syncthreads();   // sC, sE ready

    if (tid < 9) {
        const int m = tid / 3;
        const float e0 = sE[m * 3 + 0], e1 = sE[m * 3 + 1], e2 = sE[m * 3 + 2];
        const float n = sqrtf(e0 * e0 + e1 * e1 + e2 * e2);
        outE[b * 9 + tid] = sE[tid] / fmaxf(n, 1e-6f);
    }
    if (tid < 18) {
        const int which = tid / 9, mc = tid % 9;
        const int m = mc / 3, c = mc % 3;
        float acc = 0.f;
        #pragma unroll 8
        for (int i = 0; i < 64; ++i)
            acc = fmaf(sC[(1 + m) * 64 + i], iw[(2 * i + which) * 3 + c], acc);
        wsAB[b * 18 + tid] = acc;
    }
}

// ============================================================
// Kernel 2: fused monomials + coords + grid-sample + points_code.
// Round-6 structure EXCEPT phase C is compute-8/burst-8:
// compute 8 independent f4v accs into registers, then 8 back-to-back 1-KB
// contiguous wave stores with no intervening VALU/LDS (max outstanding
// stores per wave — the one untested mechanism).
// ============================================================
__global__ __launch_bounds__(384) void k_code(
    const float* __restrict__ x, const float* __restrict__ dens,
    const float* __restrict__ ws, const float* __restrict__ ib,
    float* __restrict__ out)
{
    __shared__ alignas(16) float sC[1024];
    __shared__ alignas(16) float sT[64 * 32];   // 8 KB

    const int blk   = blockIdx.x;
    const int b     = blk & 7;
    const int vbase = (blk >> 3) * 64;
    const int tid   = threadIdx.x;

    if (tid < 256)
        ((f4v*)sC)[tid] = ((const f4v*)(ws + WS_C + b * 1024))[tid];

    // ---- prologue (wave 0): monomials -> sT, coords, grid-sample ----
    if (tid < 64) {
        const int g = b * 32768 + vbase + tid;
        const float px = x[(size_t)g * 3 + 0];
        const float py = x[(size_t)g * 3 + 1];
        const float pz = x[(size_t)g * 3 + 2];
        const float r2 = px * px + py * py + pz * pz;
        const float r   = sqrtf(r2);
        const float inv = 1.f / fmaxf(r, 1e-6f);
        const float ux = px * inv, uy = py * inv, uz = pz * inv;
        const float r3 = r2 * r;

        const float z1 = 0.48860251f * uy * r;
        const float z2 = 0.48860251f * uz * r;
        const float z3 = 0.48860251f * ux * r;

        float* T = sT + tid * 32;
        T[0]  = 1.f;  T[1] = r2;  T[2] = 0.f; T[3] = 0.f;
        T[4]  = 0.f;  T[5] = 0.f; T[6] = 0.f; T[7] = 0.f;
        T[8]  = z1;   T[9] = z2;  T[10] = z3;
        T[11] = z1 * r2; T[12] = z2 * r2; T[13] = z3 * r2;
        T[14] = 0.f;  T[15] = 0.f;
        T[16] = 1.09254843f * ux * uy * r2;                          // m4
        T[17] = 1.09254843f * uy * uz * r2;                          // m5
        T[18] = 0.31539157f * (3.f * uz * uz - 1.f) * r2;            // m6
        T[19] = 1.09254843f * ux * uz * r2;                          // m7
        T[20] = 0.54627421f * (ux * ux - uy * uy) * r2;              // m8
        T[21] = 0.f; T[22] = 0.f; T[23] = 0.f;
        T[24] = 0.59004359f * uy * (3.f * ux * ux - uy * uy) * r3;   // m9
        T[25] = 2.89061144f * ux * uy * uz * r3;                     // m10
        T[26] = 0.45704579f * uy * (5.f * uz * uz - 1.f) * r3;       // m11
        T[27] = 0.37317633f * uz * (5.f * uz * uz - 3.f) * r3;       // m12
        T[28] = 0.45704579f * ux * (5.f * uz * uz - 1.f) * r3;       // m13
        T[29] = 1.44530572f * uz * (ux * ux - uy * uy) * r3;         // m14
        T[30] = 0.59004359f * ux * (ux * ux - 3.f * uy * uy) * r3;   // m15
        T[31] = 0.f;

        // coords + grid-sample
        const float* AB = ws + WS_AB + b * 18;
        float pt[3];
        #pragma unroll
        for (int cc = 0; cc < 3; ++cc) {
            float acc = ib[cc];
            acc = fmaf(z1, AB[0 + cc] + r2 * AB[9  + cc], acc);
            acc = fmaf(z2, AB[3 + cc] + r2 * AB[12 + cc], acc);
            acc = fmaf(z3, AB[6 + cc] + r2 * AB[15 + cc], acc);
            pt[cc] = acc;
            out[OFF_COORD + (size_t)g * 3 + cc] = acc;
        }
        const float ixf = (pt[0] + 1.f) * 0.5f * 31.f;
        const float iyf = (pt[1] + 1.f) * 0.5f * 31.f;
        const float izf = (pt[2] + 1.f) * 0.5f * 31.f;
        const float x0f = floorf(ixf), y0f = floorf(iyf), z0f = floorf(izf);
        const float wx = ixf - x0f, wy = iyf - y0f, wz = izf - z0f;
        const int x0 = (int)x0f, y0 = (int)y0f, z0 = (int)z0f;
        const float* volb = dens + (size_t)b * 32768;
        float s = 0.f;
        #pragma unroll
        for (int dz = 0; dz < 2; ++dz) {
            const int zi = z0 + dz;
            const float wzz = dz ? wz : 1.f - wz;
            #pragma unroll
            for (int dy = 0; dy < 2; ++dy) {
                const int yi = y0 + dy;
                const float wyy = dy ? wy : 1.f - wy;
                #pragma unroll
                for (int dx = 0; dx < 2; ++dx) {
                    const int xi = x0 + dx;
                    const float wxx = dx ? wx : 1.f - wx;
                    if (zi >= 0 && zi < 32 && yi >= 0 && yi < 32 && xi >= 0 && xi < 32)
                        s += wzz * wyy * wxx * volb[zi * 1024 + yi * 32 + xi];
                }
            }
        }
        out[g] = s;
    }
    __syncthreads();

    // ---- per-lane constant setup (identical to round 6) ----
    const int w  = tid >> 6, l = tid & 63;
    const int g0 = w * 256 + 4 * l;          // flat float index within a 4-row stripe
    const int rw = g0 / 384;                 // 0..3: row offset within stripe
    const int c  = g0 - rw * 384;            // channel-quad base (multiple of 4)

    f4v cf0 = {0.f,0.f,0.f,0.f}, cf1 = cf0, cf2 = cf0, cf3 = cf0;
    f4v cf4 = cf0, cf5 = cf0, cf6 = cf0;
    int tb;
    if (c < 128) {
        const int i0 = c >> 1;
        const float ca = sC[i0]     * 0.28209479f;
        const float cb = sC[i0 + 1] * 0.28209479f;
        cf0 = (f4v){ca, 0.f, cb, 0.f};
        cf1 = (f4v){0.f, ca, 0.f, cb};
        tb = 0;
    } else if (c < 256) {
        const int u = (c - 128) >> 1;
        const float a0 = sC[64 + u],     a1 = sC[128 + u],     a2 = sC[192 + u];
        const float b0 = sC[64 + u + 1], b1 = sC[128 + u + 1], b2 = sC[192 + u + 1];
        cf0 = (f4v){a0, 0.f, b0, 0.f};
        cf1 = (f4v){a1, 0.f, b1, 0.f};
        cf2 = (f4v){a2, 0.f, b2, 0.f};
        cf3 = (f4v){0.f, a0, 0.f, b0};
        cf4 = (f4v){0.f, a1, 0.f, b1};
        cf5 = (f4v){0.f, a2, 0.f, b2};
        tb = 8;
    } else if (c < 320) {
        const int i0 = c - 256;
        cf0 = *(const f4v*)&sC[4 * 64 + i0];
        cf1 = *(const f4v*)&sC[5 * 64 + i0];
        cf2 = *(const f4v*)&sC[6 * 64 + i0];
        cf3 = *(const f4v*)&sC[7 * 64 + i0];
        cf4 = *(const f4v*)&sC[8 * 64 + i0];
        tb = 16;
    } else {
        const int i0 = c - 320;
        cf0 = *(const f4v*)&sC[ 9 * 64 + i0];
        cf1 = *(const f4v*)&sC[10 * 64 + i0];
        cf2 = *(const f4v*)&sC[11 * 64 + i0];
        cf3 = *(const f4v*)&sC[12 * 64 + i0];
        cf4 = *(const f4v*)&sC[13 * 64 + i0];
        cf5 = *(const f4v*)&sC[14 * 64 + i0];
        cf6 = *(const f4v*)&sC[15 * 64 + i0];
        tb = 24;
    }

    const float* Tb = sT + tb;
    float* po = out + OFF_CODE + ((size_t)(b * 32768 + vbase)) * 384 + g0;

    // ---- 2 half-bursts: compute 8 independent accs, then 8 back-to-back
    //      1-KB contiguous wave stores (no VALU/LDS between stores) ----
    #pragma unroll
    for (int h = 0; h < 2; ++h) {
        f4v acc[8];
        #pragma unroll
        for (int p = 0; p < 8; ++p) {
            const int ro = (4 * (h * 8 + p) + rw) * 32;
            const f4v ta  = *(const f4v*)(Tb + ro);
            const f4v tb4 = *(const f4v*)(Tb + ro + 4);
            f4v a = cf0 * ta.x;
            a += cf1 * ta.y;
            a += cf2 * ta.z;
            a += cf3 * ta.w;
            a += cf4 * tb4.x;
            a += cf5 * tb4.y;
            a += cf6 * tb4.z;
            acc[p] = a;
        }
        float* pb = po + (size_t)h * 8 * 1536;
        #pragma unroll
        for (int p = 0; p < 8; ++p)
            *(f4v*)(pb + (size_t)p * 1536) = acc[p];
    }
}

// ============================================================
extern "C" void kernel_launch(void* const* d_in, const int* in_sizes, int n_in,
                              void* d_out, int out_size, void* d_ws, size_t ws_size,
                              hipStream_t stream) {
    const float* x    = (const float*)d_in[0];
    const float* dens = (const float*)d_in[1];
    const float* F    = (const float*)d_in[2];
    const float* S2   = (const float*)d_in[3];
    const float* bw1  = (const float*)d_in[4];
    const float* bb1  = (const float*)d_in[5];
    const float* bw2  = (const float*)d_in[6];
    const float* bb2  = (const float*)d_in[7];
    const float* cw1  = (const float*)d_in[8];
    const float* cb1  = (const float*)d_in[9];
    const float* cw2  = (const float*)d_in[10];
    const float* cb2  = (const float*)d_in[11];
    const float* iw   = (const float*)d_in[12];
    const float* ib   = (const float*)d_in[13];
    float* out = (float*)d_out;
    float* ws  = (float*)d_ws;

    k_hidden<<<64,   384, 0, stream>>>(F, bw1, bb1, cw1, cb1, ws);
    k_coeffs<<<8,    512, 0, stream>>>(ws, S2, bw2, bb2, cw2, cb2, iw, ws, out + OFF_E);
    k_code<<<4096,   384, 0, stream>>>(x, dens, ws, ib, out);
}